// Round 4
// baseline (118.106 us; speedup 1.0000x reference)
//
#include <hip/hip_runtime.h>

// Problem constants (fixed by the reference setup)
#define B_ 128
#define N_ 65536
#define P_ 4096
#define T_ 32
#define D_ 2
#define K_ 4
#define S_ 8                       // slices per batch
#define PPB 512                    // pairs per block (P_/S_)
#define MAGIC 0x5A5A7A7Au          // != 0xAAAAAAAA ws poison

// sorted-descending top-4 insert chain (7 ops)
#define INS(v0, v1, v2, v3, val)                                  \
    {                                                             \
        float _x = fminf(v0, val); v0 = fmaxf(v0, val);           \
        float _y = fminf(v1, _x);  v1 = fmaxf(v1, _x);            \
        float _z = fminf(v2, _y);  v2 = fmaxf(v2, _y);            \
        v3 = fmaxf(v3, _z);                                       \
    }

// ---------------------------------------------------------------------------
// Single fused kernel. Block = (batch, slice) of 512 pairs:
//  1. gather b/d from fun (XCD swizzle: one batch's 8 slices on one XCD;
//     16 batches x 256 KB = 4 MB = one XCD's L2)
//  2. partition pairs by homology dim into LDS (ballot ranks; order within a
//     dim segment is irrelevant for top-k; odd ends get sentinel (4,-4))
//  3. scan two same-dim pairs per wave iteration (lanes 0-31 pair j, lanes
//     32-63 pair j+1; each half covers all 32 t values; no dim select)
//  4. shfl_xor(32) + LDS merge -> wave 0 holds the slice's 64 combo top-4s
//  5. slices 1..7: write partial, device fence, set MAGIC flag.
//     slice 0: spin on the 7 flags, acquire-fence, merge, write out.
// ---------------------------------------------------------------------------
__global__ __launch_bounds__(256, 4) void fused_all(
        const float* __restrict__ fun,
        const int* __restrict__ bidx,
        const int* __restrict__ didx,
        const int* __restrict__ pdim,
        float* __restrict__ partial,
        unsigned int* __restrict__ flags,
        float* __restrict__ out) {
    __shared__ float2 bdS[PPB + 8];
    __shared__ int    cntS[8];
    __shared__ float  mrg[4][64][4];

    int bid   = blockIdx.x;               // 0..1023
    int xcd   = bid & 7;
    int seq   = bid >> 3;                 // 0..127
    int batch = xcd * 16 + (seq & 15);    // all 8 slices of a batch on one XCD
    int slice = seq >> 4;                 // 0..7

    int tid  = threadIdx.x;
    int lane = tid & 63;
    int wave = tid >> 6;
    int base = batch * P_ + slice * PPB;

    // --- gather (coalesced index reads; fun row is L2-resident) ---
    const float* f = fun + (size_t)batch * N_;
    int p0 = base + tid, p1 = base + 256 + tid;
    int bi0 = bidx[p0], di0 = didx[p0];
    int bi1 = bidx[p1], di1 = didx[p1];
    int pd0 = pdim[p0], pd1 = pdim[p1];
    float b0 = f[bi0], d0 = f[di0];
    float b1 = f[bi1], d1 = f[di1];

    // --- partition by dim: set s = wave*2+{0,1}, 64 pairs each ---
    unsigned long long bal0 = __ballot(pd0 == 0);
    unsigned long long bal1 = __ballot(pd1 == 0);
    if (lane == 0) {
        cntS[wave * 2]     = __popcll(bal0);
        cntS[wave * 2 + 1] = __popcll(bal1);
    }
    __syncthreads();

    int s0 = wave * 2, s1 = s0 + 1;
    int pre0_s0 = 0, pre1_s0 = 0, pre0_s1 = 0, pre1_s1 = 0, n0tot = 0;
    #pragma unroll
    for (int s = 0; s < 8; ++s) {
        int cs = cntS[s];
        if (s < s0) { pre0_s0 += cs; pre1_s0 += 64 - cs; }
        if (s < s1) { pre0_s1 += cs; pre1_s1 += 64 - cs; }
        n0tot += cs;
    }
    int n1tot = PPB - n0tot;
    int A   = (n0tot + 1) & ~1;           // dim0 segment padded length
    int n1p = (n1tot + 1) & ~1;           // dim1 segment padded length

    unsigned long long lmask = (1ull << lane) - 1ull;
    int r0 = __popcll(bal0 & lmask);
    int r1 = __popcll(bal1 & lmask);
    int dst0 = (pd0 == 0) ? (pre0_s0 + r0) : (A + pre1_s0 + (lane - r0));
    int dst1 = (pd1 == 0) ? (pre0_s1 + r1) : (A + pre1_s1 + (lane - r1));
    bdS[dst0] = make_float2(b0, d0);
    bdS[dst1] = make_float2(b1, d1);
    if (tid == 0 && (n0tot & 1)) bdS[n0tot]     = make_float2(4.f, -4.f);
    if (tid == 1 && (n1tot & 1)) bdS[A + n1tot] = make_float2(4.f, -4.f);
    __syncthreads();

    // --- scan: two same-dim pairs per wave iteration ---
    int half = lane >> 5;
    int t    = lane & 31;
    float tf = (float)(t + 1) * 0.03125f; // tseq[t], exact in fp32

    float a0 = 0.f, a1 = 0.f, a2 = 0.f, a3 = 0.f;  // dim0 partial top-4
    float c0 = 0.f, c1 = 0.f, c2 = 0.f, c3 = 0.f;  // dim1 partial top-4

    #pragma unroll 4
    for (int j = wave * 2; j < A; j += 8) {
        float2 pr = bdS[j + half];
        float val = fminf(tf - pr.x, pr.y - tf);
        INS(a0, a1, a2, a3, val);
    }
    #pragma unroll 4
    for (int j = A + wave * 2; j < A + n1p; j += 8) {
        float2 pr = bdS[j + half];
        float val = fminf(tf - pr.x, pr.y - tf);
        INS(c0, c1, c2, c3, val);
    }

    // --- even/odd half merge: partner lane l^32 holds same (t, dim) work ---
    float u0 = (half == 0) ? a0 : c0, w0 = (half == 0) ? c0 : a0;
    float u1 = (half == 0) ? a1 : c1, w1 = (half == 0) ? c1 : a1;
    float u2 = (half == 0) ? a2 : c2, w2 = (half == 0) ? c2 : a2;
    float u3 = (half == 0) ? a3 : c3, w3 = (half == 0) ? c3 : a3;
    float q;
    q = __shfl_xor(w0, 32); INS(u0, u1, u2, u3, q);
    q = __shfl_xor(w1, 32); INS(u0, u1, u2, u3, q);
    q = __shfl_xor(w2, 32); INS(u0, u1, u2, u3, q);
    q = __shfl_xor(w3, 32); INS(u0, u1, u2, u3, q);
    // lane l now holds top-4 for combo = l (dim = l>>5, t = l&31)

    mrg[wave][lane][0] = u0;
    mrg[wave][lane][1] = u1;
    mrg[wave][lane][2] = u2;
    mrg[wave][lane][3] = u3;
    __syncthreads();

    if (wave != 0) return;

    // --- block merge (wave 0 only): slice's top-4 for all 64 combos ---
    float v0 = 0.f, v1 = 0.f, v2 = 0.f, v3 = 0.f;
    #pragma unroll
    for (int w = 0; w < 4; ++w) {
        #pragma unroll
        for (int k = 0; k < 4; ++k) {
            float val = mrg[w][lane][k];
            INS(v0, v1, v2, v3, val);
        }
    }

    if (slice != 0) {
        // producer: publish partial, then release the flag
        float4* dstp = (float4*)(partial + (((size_t)batch * S_ + slice) * 64 + lane) * 4);
        *dstp = make_float4(v0, v1, v2, v3);
        __threadfence();              // wave-uniform: drains this wave's stores, L2 writeback
        if (lane == 0) {
            __hip_atomic_store(&flags[batch * S_ + slice], MAGIC,
                               __ATOMIC_RELEASE, __HIP_MEMORY_SCOPE_AGENT);
        }
    } else {
        // consumer: wait for the 7 sibling slices of this batch
        unsigned int* fl = &flags[batch * S_];
        bool need = (lane >= 1) && (lane < S_);
        for (;;) {
            unsigned int fv = need
                ? __hip_atomic_load(&fl[lane], __ATOMIC_ACQUIRE, __HIP_MEMORY_SCOPE_AGENT)
                : MAGIC;
            if (__ballot(fv != MAGIC) == 0ull) break;
            __builtin_amdgcn_s_sleep(2);
        }
        __threadfence();              // acquire side: invalidate stale cache
        const float4* src = (const float4*)(partial + ((size_t)batch * S_ * 64 + lane) * 4);
        #pragma unroll
        for (int s = 1; s < S_; ++s) {
            float4 val4 = src[(size_t)s * 64];
            INS(v0, v1, v2, v3, val4.x);
            INS(v0, v1, v2, v3, val4.y);
            INS(v0, v1, v2, v3, val4.z);
            INS(v0, v1, v2, v3, val4.w);
        }
        // out[batch*256 + combo*4 + k], combo = lane -> [B, D, T, K]
        *(float4*)(out + ((size_t)batch * 64 + lane) * 4) = make_float4(v0, v1, v2, v3);
    }
}

extern "C" void kernel_launch(void* const* d_in, const int* in_sizes, int n_in,
                              void* d_out, int out_size, void* d_ws, size_t ws_size,
                              hipStream_t stream) {
    const float* fun  = (const float*)d_in[0]; // [B, N] f32
    const int*   bidx = (const int*)d_in[1];   // [B, P] i32
    const int*   didx = (const int*)d_in[2];   // [B, P] i32
    const int*   pdim = (const int*)d_in[3];   // [B, P] i32
    float* out = (float*)d_out;                // [B, D, T, K] f32

    float*        partial = (float*)d_ws;                        // 1 MB
    unsigned int* flags   = (unsigned int*)((char*)d_ws + (size_t)B_ * S_ * 64 * 4 * 4);

    fused_all<<<B_ * S_, 256, 0, stream>>>(fun, bidx, didx, pdim,
                                           partial, flags, out);
}

// Round 6
// 91.652 us; speedup vs baseline: 1.2886x; 1.2886x over previous
//
#include <hip/hip_runtime.h>

// Problem constants (fixed by the reference setup)
#define B_ 128
#define N_ 65536
#define P_ 4096
#define T_ 32
#define D_ 2
#define K_ 4
#define S_ 8                       // slices per batch
#define PPB 512                    // pairs per block (P_/S_)

// sorted-descending top-4 insert chain (7 ops)
#define INS(v0, v1, v2, v3, val)                                  \
    {                                                             \
        float _x = fminf(v0, val); v0 = fmaxf(v0, val);           \
        float _y = fminf(v1, _x);  v1 = fmaxf(v1, _x);            \
        float _z = fminf(v2, _y);  v2 = fmaxf(v2, _y);            \
        v3 = fmaxf(v3, _z);                                       \
    }

// ---------------------------------------------------------------------------
// Kernel 1: each block owns (batch, slice) = 512 pairs (2 per thread).
//  Phase A (memory): issue int2 index loads, then async-prefetch this block's
//    32 KB share of the batch's fun row toward L2 via global_load_lds
//    (coalesced 16 B/lane; LDS dest is scratch we overwrite later). The
//    prefetch overlaps the idx loads, so the random gathers that follow hit
//    a warm L2 instead of L3/HBM (R4 counters showed the gather phase is
//    miss-latency bound: VALUBusy 10%, HBM 4.5%).
//  Phase B: partition pairs by homology dim into LDS (ballot ranks; order
//    within a dim segment is irrelevant for top-k; odd ends get a sentinel
//    pair (4,-4) whose tent is always negative).
//  Phase C: scan two same-dim pairs per wave iteration (lanes 0-31 pair j,
//    lanes 32-63 pair j+1; each half covers all 32 t values; no dim select),
//    then shfl_xor(32) + LDS merge; wave 0 writes the slice partial.
// ---------------------------------------------------------------------------
__global__ __launch_bounds__(256) void fused_scan(
        const float* __restrict__ fun,
        const int* __restrict__ bidx,
        const int* __restrict__ didx,
        const int* __restrict__ pdim,
        float* __restrict__ partial) {
    __shared__ float2 bdS[PPB + 8];
    __shared__ int    cntS[8];
    __shared__ float  mrg[4][64][4];   // merge buffer; also prefetch scratch

    int bid   = blockIdx.x;               // 0..1023
    int xcd   = bid & 7;
    int seq   = bid >> 3;                 // 0..127
    int batch = xcd * 16 + (seq & 15);    // heuristic: batch's slices share XCD
    int slice = seq >> 4;                 // 0..7

    int tid  = threadIdx.x;
    int lane = tid & 63;
    int wave = tid >> 6;
    int base = batch * P_ + slice * PPB;

    // --- Phase A: index loads (int2, adjacent pairs) ---
    const int2* b2 = (const int2*)(bidx + base);
    const int2* d2 = (const int2*)(didx + base);
    const int2* p2 = (const int2*)(pdim + base);
    int2 bi = b2[tid];
    int2 di = d2[tid];
    int2 pd = p2[tid];

    // async prefetch: this block's 32 KB share of the fun row -> L2 (+ LDS
    // scratch we never read). Per wave: 8 iters x (64 lanes x 16 B) = 8 KB.
    // global addr is per-lane; LDS dest is wave-uniform base + lane*16
    // (implicit scatter); offset arg must be a constant.
    {
        const float* chunk = fun + (size_t)batch * N_ + slice * 8192
                           + wave * 2048 + lane * 4;
        char* ldsdst = (char*)&mrg[wave][0][0];  // 1 KB scratch per wave
        #pragma unroll
        for (int k = 0; k < 8; ++k) {
            __builtin_amdgcn_global_load_lds(
                (const __attribute__((address_space(1))) unsigned int*)(chunk + k * 256),
                (__attribute__((address_space(3))) unsigned int*)ldsdst,
                16, 0, 0);
        }
    }

    // dependent gathers (fun row now L2-warming underneath)
    const float* f = fun + (size_t)batch * N_;
    float b0 = f[bi.x], d0 = f[di.x];
    float b1 = f[bi.y], d1 = f[di.y];
    int pd0 = pd.x, pd1 = pd.y;

    // --- Phase B: partition by dim. Each wave contributes two 64-pair sets
    // (set s0 = even pairs of this wave's 128, s1 = odd). ---
    unsigned long long bal0 = __ballot(pd0 == 0);
    unsigned long long bal1 = __ballot(pd1 == 0);
    if (lane == 0) {
        cntS[wave * 2]     = __popcll(bal0);
        cntS[wave * 2 + 1] = __popcll(bal1);
    }
    __syncthreads();

    int s0 = wave * 2, s1 = s0 + 1;
    int pre0_s0 = 0, pre1_s0 = 0, pre0_s1 = 0, pre1_s1 = 0, n0tot = 0;
    #pragma unroll
    for (int s = 0; s < 8; ++s) {
        int cs = cntS[s];
        if (s < s0) { pre0_s0 += cs; pre1_s0 += 64 - cs; }
        if (s < s1) { pre0_s1 += cs; pre1_s1 += 64 - cs; }
        n0tot += cs;
    }
    int n1tot = PPB - n0tot;
    int A   = (n0tot + 1) & ~1;           // dim0 segment padded length
    int n1p = (n1tot + 1) & ~1;           // dim1 segment padded length

    unsigned long long lmask = (1ull << lane) - 1ull;
    int r0 = __popcll(bal0 & lmask);
    int r1 = __popcll(bal1 & lmask);
    int dst0 = (pd0 == 0) ? (pre0_s0 + r0) : (A + pre1_s0 + (lane - r0));
    int dst1 = (pd1 == 0) ? (pre0_s1 + r1) : (A + pre1_s1 + (lane - r1));
    bdS[dst0] = make_float2(b0, d0);
    bdS[dst1] = make_float2(b1, d1);
    if (tid == 0 && (n0tot & 1)) bdS[n0tot]     = make_float2(4.f, -4.f);
    if (tid == 1 && (n1tot & 1)) bdS[A + n1tot] = make_float2(4.f, -4.f);
    __syncthreads();

    // --- Phase C: scan, two same-dim pairs per wave iteration ---
    int half = lane >> 5;
    int t    = lane & 31;
    float tf = (float)(t + 1) * 0.03125f; // tseq[t], exact in fp32

    float a0 = 0.f, a1 = 0.f, a2 = 0.f, a3 = 0.f;  // dim0 partial top-4
    float c0 = 0.f, c1 = 0.f, c2 = 0.f, c3 = 0.f;  // dim1 partial top-4

    #pragma unroll 4
    for (int j = wave * 2; j < A; j += 8) {
        float2 pr = bdS[j + half];
        float val = fminf(tf - pr.x, pr.y - tf);
        INS(a0, a1, a2, a3, val);
    }
    #pragma unroll 4
    for (int j = A + wave * 2; j < A + n1p; j += 8) {
        float2 pr = bdS[j + half];
        float val = fminf(tf - pr.x, pr.y - tf);
        INS(c0, c1, c2, c3, val);
    }

    // --- even/odd half merge: partner lane l^32 holds same (t, dim) work ---
    float u0 = (half == 0) ? a0 : c0, w0 = (half == 0) ? c0 : a0;
    float u1 = (half == 0) ? a1 : c1, w1 = (half == 0) ? c1 : a1;
    float u2 = (half == 0) ? a2 : c2, w2 = (half == 0) ? c2 : a2;
    float u3 = (half == 0) ? a3 : c3, w3 = (half == 0) ? c3 : a3;
    float q;
    q = __shfl_xor(w0, 32); INS(u0, u1, u2, u3, q);
    q = __shfl_xor(w1, 32); INS(u0, u1, u2, u3, q);
    q = __shfl_xor(w2, 32); INS(u0, u1, u2, u3, q);
    q = __shfl_xor(w3, 32); INS(u0, u1, u2, u3, q);
    // lane l now holds top-4 for combo = l (dim = l>>5, t = l&31)

    mrg[wave][lane][0] = u0;
    mrg[wave][lane][1] = u1;
    mrg[wave][lane][2] = u2;
    mrg[wave][lane][3] = u3;
    __syncthreads();

    if (wave == 0) {
        float v0 = 0.f, v1 = 0.f, v2 = 0.f, v3 = 0.f;
        #pragma unroll
        for (int w = 0; w < 4; ++w) {
            #pragma unroll
            for (int k = 0; k < 4; ++k) {
                float val = mrg[w][lane][k];
                INS(v0, v1, v2, v3, val);
            }
        }
        float4* dstp = (float4*)(partial + (((size_t)batch * S_ + slice) * 64 + lane) * 4);
        *dstp = make_float4(v0, v1, v2, v3);
    }
}

// ---------------------------------------------------------------------------
// Kernel 2: fold the 8 slice-partials per (batch, combo) into the final top-4.
// out index = batch*256 + combo*4 + k matches reference [B, D, T, K].
// ---------------------------------------------------------------------------
__global__ __launch_bounds__(256) void final_merge(
        const float* __restrict__ partial,
        float* __restrict__ out) {
    int tid   = blockIdx.x * 256 + threadIdx.x; // 0 .. B_*64-1
    int batch = tid >> 6;
    int combo = tid & 63;
    float v0 = 0.f, v1 = 0.f, v2 = 0.f, v3 = 0.f;
    const float4* src = (const float4*)(partial + ((size_t)batch * S_ * 64 + combo) * 4);
    #pragma unroll
    for (int s = 0; s < S_; ++s) {
        float4 val4 = src[(size_t)s * 64];
        INS(v0, v1, v2, v3, val4.x);
        INS(v0, v1, v2, v3, val4.y);
        INS(v0, v1, v2, v3, val4.z);
        INS(v0, v1, v2, v3, val4.w);
    }
    *(float4*)(out + (size_t)tid * 4) = make_float4(v0, v1, v2, v3);
}

extern "C" void kernel_launch(void* const* d_in, const int* in_sizes, int n_in,
                              void* d_out, int out_size, void* d_ws, size_t ws_size,
                              hipStream_t stream) {
    const float* fun  = (const float*)d_in[0]; // [B, N] f32
    const int*   bidx = (const int*)d_in[1];   // [B, P] i32
    const int*   didx = (const int*)d_in[2];   // [B, P] i32
    const int*   pdim = (const int*)d_in[3];   // [B, P] i32
    float* out = (float*)d_out;                // [B, D, T, K] f32

    float* partial = (float*)d_ws;             // B*S*64*4 f32 = 1 MB

    fused_scan<<<B_ * S_, 256, 0, stream>>>(fun, bidx, didx, pdim, partial);
    final_merge<<<(B_ * 64) / 256, 256, 0, stream>>>(partial, out);
}

// Round 7
// 89.876 us; speedup vs baseline: 1.3141x; 1.0198x over previous
//
#include <hip/hip_runtime.h>

// Problem constants (fixed by the reference setup)
#define B_ 128
#define N_ 65536
#define P_ 4096
#define T_ 32
#define D_ 2
#define K_ 4

// sorted-descending top-4 insert chain (7 ops)
#define INS(v0, v1, v2, v3, val)                                  \
    {                                                             \
        float _x = fminf(v0, val); v0 = fmaxf(v0, val);           \
        float _y = fminf(v1, _x);  v1 = fmaxf(v1, _x);            \
        float _z = fminf(v2, _y);  v2 = fmaxf(v2, _y);            \
        v3 = fmaxf(v3, _z);                                       \
    }

// ---------------------------------------------------------------------------
// Single kernel, block = (batch, dim): 256 blocks x 512 threads (8 waves).
//  - Each thread reads 8 consecutive pairs' bidx/didx/pdim via int4 loads
//    (coalesced; idx arrays read once per (batch,dim), i.e. twice total).
//  - Conditional gather: only pairs with pdim == mydim issue fun gathers
//    (inactive lanes generate no TA requests -> same total gather work as
//    the old partition-all scheme, but no partition LDS pass, no barrier).
//  - Ballot-compact kept (b,d) float2 into a PRIVATE per-wave LDS segment
//    (wave-uniform running offset in SGPRs; no cross-wave prefix needed).
//    Odd segment ends get a sentinel (4,-4) whose tent is always negative.
//  - Scan: lanes 0-31 process even entries, 32-63 odd; t = lane&31; each
//    entry is shared by 32 lanes (LDS 2-address broadcast, free).
//  - shfl_xor(32) merges the halves; one __syncthreads; wave 0 merges the 8
//    wave-partials and writes out[batch, dim, t, 0..3] as float4.
//  No workspace, no second kernel, no inter-block communication.
// ---------------------------------------------------------------------------
__global__ __launch_bounds__(512) void fused_pl(
        const float* __restrict__ fun,
        const int* __restrict__ bidx,
        const int* __restrict__ didx,
        const int* __restrict__ pdim,
        float* __restrict__ out) {
    __shared__ float2 bdS[8][512];     // per-wave compact segments (32 KB)
    __shared__ float  mrg[8][32][4];   // per-wave merged top-4 (4 KB)

    int bid   = blockIdx.x;            // 0..255
    int xcd   = bid & 7;
    int seq   = bid >> 3;              // 0..31
    int batch = xcd * 16 + (seq & 15); // heuristic: a batch's 2 blocks + 15
    int mydim = seq >> 4;              //   neighbors share an XCD's L2

    int tid  = threadIdx.x;
    int lane = tid & 63;
    int wave = tid >> 6;

    // this thread's 8 consecutive pairs (int4-coalesced)
    int pbase = batch * P_ + wave * 512 + lane * 8;
    const int4* bp = (const int4*)(bidx + pbase);
    const int4* dp = (const int4*)(didx + pbase);
    const int4* pp = (const int4*)(pdim + pbase);
    int4 bi0 = bp[0], bi1 = bp[1];
    int4 di0 = dp[0], di1 = dp[1];
    int4 pd0 = pp[0], pd1 = pp[1];

    const float* f = fun + (size_t)batch * N_;
    float2* seg = &bdS[wave][0];
    unsigned long long lm = (1ull << lane) - 1ull;
    int off = 0;  // wave-uniform running count (stays scalar)

#define ROUND(PD, BI, DI)                                         \
    {                                                             \
        bool keep = ((PD) == mydim);                              \
        unsigned long long bal = __ballot(keep);                  \
        if (keep) {                                               \
            int rank = __popcll(bal & lm);                        \
            float b = f[(BI)];                                    \
            float d = f[(DI)];                                    \
            seg[off + rank] = make_float2(b, d);                  \
        }                                                         \
        off += __popcll(bal);                                     \
    }
    ROUND(pd0.x, bi0.x, di0.x)
    ROUND(pd0.y, bi0.y, di0.y)
    ROUND(pd0.z, bi0.z, di0.z)
    ROUND(pd0.w, bi0.w, di0.w)
    ROUND(pd1.x, bi1.x, di1.x)
    ROUND(pd1.y, bi1.y, di1.y)
    ROUND(pd1.z, bi1.z, di1.z)
    ROUND(pd1.w, bi1.w, di1.w)
#undef ROUND

    if (lane == 0 && (off & 1)) seg[off] = make_float2(4.f, -4.f);
    int cnt = (off + 1) & ~1;          // even length incl. sentinel

    // --- scan: halves take even/odd entries; t = lane & 31 ---
    int half = lane >> 5;
    int t    = lane & 31;
    float tf = (float)(t + 1) * 0.03125f; // tseq[t], exact in fp32

    float v0 = 0.f, v1 = 0.f, v2 = 0.f, v3 = 0.f;
    #pragma unroll 4
    for (int j = half; j < cnt; j += 2) {
        float2 pr = seg[j];
        float val = fminf(tf - pr.x, pr.y - tf);
        INS(v0, v1, v2, v3, val);
    }

    // --- merge halves: snapshot partner's top-4, then insert ---
    float m0 = __shfl_xor(v0, 32);
    float m1 = __shfl_xor(v1, 32);
    float m2 = __shfl_xor(v2, 32);
    float m3 = __shfl_xor(v3, 32);
    INS(v0, v1, v2, v3, m0);
    INS(v0, v1, v2, v3, m1);
    INS(v0, v1, v2, v3, m2);
    INS(v0, v1, v2, v3, m3);

    if (half == 0) {
        mrg[wave][t][0] = v0;
        mrg[wave][t][1] = v1;
        mrg[wave][t][2] = v2;
        mrg[wave][t][3] = v3;
    }
    __syncthreads();

    if (wave == 0 && half == 0) {
        float u0 = 0.f, u1 = 0.f, u2 = 0.f, u3 = 0.f;
        #pragma unroll
        for (int w = 0; w < 8; ++w) {
            float4 val4 = *(const float4*)&mrg[w][t][0];
            INS(u0, u1, u2, u3, val4.x);
            INS(u0, u1, u2, u3, val4.y);
            INS(u0, u1, u2, u3, val4.z);
            INS(u0, u1, u2, u3, val4.w);
        }
        // out[batch, mydim, t, 0..3]
        *(float4*)(out + ((size_t)batch * 64 + mydim * 32 + t) * 4) =
            make_float4(u0, u1, u2, u3);
    }
}

extern "C" void kernel_launch(void* const* d_in, const int* in_sizes, int n_in,
                              void* d_out, int out_size, void* d_ws, size_t ws_size,
                              hipStream_t stream) {
    const float* fun  = (const float*)d_in[0]; // [B, N] f32
    const int*   bidx = (const int*)d_in[1];   // [B, P] i32
    const int*   didx = (const int*)d_in[2];   // [B, P] i32
    const int*   pdim = (const int*)d_in[3];   // [B, P] i32
    float* out = (float*)d_out;                // [B, D, T, K] f32

    fused_pl<<<B_ * D_, 512, 0, stream>>>(fun, bidx, didx, pdim, out);
}